// Round 6
// baseline (378.876 us; speedup 1.0000x reference)
//
#include <hip/hip_runtime.h>

// out[b,n,m] = dot(m1[b,n,:], w[:512]) + dot(m2[b,m,:], w[512:]) + bias[0]
// B=8, N1=N2=2048, D=512, float32. Mandatory HBM: 67 MB read + 134 MB write.
//
// Single fused kernel with per-batch producer/consumer flags:
//   each wave (4096 total, 512 per batch):
//     1. issue 4 m2-row loads + 4 m1-row loads (16x16B/lane outstanding)
//     2. dot+butterfly m2 rows -> s2 slice -> release atomicAdd(flags[b])
//     3. dot+butterfly m1 rows (independent of s2, hides spin)
//     4. spin until flags[b]==512 (acquire, agent scope)
//     5. read s2[b,:] (L2-hot) -> 4 full-width output rows (32 KB stores)
// All reads issue in one dense phase; only the stores wait on the flag.
// Deadlock-free: every block produces BEFORE spinning, and
// __launch_bounds__(256,4) caps VGPRs at 128 so all 1024 blocks co-reside
// (4 blocks/CU x 256 CUs = 1024).
// flags (32 B in d_ws) reset each call via hipMemsetAsync (graph-legal).

#define DDIM 512
#define BB   8
#define NN   2048
#define ROWS (BB * NN)            // 16384 rows per matrix
#define RPW  4                    // rows per wave
#define NWAVES (ROWS / RPW)       // 4096
#define WPB  (NWAVES / BB)        // 512 waves per batch

typedef float f32x4 __attribute__((ext_vector_type(4)));

__global__ __launch_bounds__(256, 4)
void fused_all(const float* __restrict__ m1,
               const float* __restrict__ m2,
               const float* __restrict__ w,
               const float* __restrict__ bias,
               float* __restrict__ s2,
               unsigned int* __restrict__ flags,
               float* __restrict__ out) {
    int wave = (int)((blockIdx.x * blockDim.x + threadIdx.x) >> 6);  // 0..4095
    int lane = threadIdx.x & 63;
    int row0 = wave * RPW;            // [0,16384): both s2-row and out-row base
    int b    = wave >> 9;             // wave / 512 = batch

    const f32x4* wv1 = reinterpret_cast<const f32x4*>(w);
    const f32x4* wv2 = reinterpret_cast<const f32x4*>(w + DDIM);
    f32x4 w2a = wv2[lane], w2b = wv2[lane + 64];
    f32x4 w1a = wv1[lane], w1b = wv1[lane + 64];

    // ---- issue all row loads (m2 first: producer critical path) ----
    f32x4 c0[RPW], c1[RPW];           // m2 rows
    #pragma unroll
    for (int r = 0; r < RPW; ++r) {
        const f32x4* rp = reinterpret_cast<const f32x4*>(m2 + (size_t)(row0 + r) * DDIM);
        c0[r] = rp[lane];
        c1[r] = rp[lane + 64];
    }
    f32x4 a0[RPW], a1[RPW];           // m1 rows
    #pragma unroll
    for (int r = 0; r < RPW; ++r) {
        const f32x4* rp = reinterpret_cast<const f32x4*>(m1 + (size_t)(row0 + r) * DDIM);
        a0[r] = rp[lane];
        a1[r] = rp[lane + 64];
    }

    // ---- produce s2 slice ----
    float accs2[RPW];
    #pragma unroll
    for (int r = 0; r < RPW; ++r)
        accs2[r] = c0[r].x * w2a.x + c0[r].y * w2a.y + c0[r].z * w2a.z + c0[r].w * w2a.w
                 + c1[r].x * w2b.x + c1[r].y * w2b.y + c1[r].z * w2b.z + c1[r].w * w2b.w;
    #pragma unroll
    for (int r = 0; r < RPW; ++r) {
        #pragma unroll
        for (int off = 1; off < 64; off <<= 1)
            accs2[r] += __shfl_xor(accs2[r], off, 64);
    }
    if (lane == 0) {
        #pragma unroll
        for (int r = 0; r < RPW; ++r)
            s2[row0 + r] = accs2[r];
        // release: make the s2 stores visible at agent scope, then count.
        __hip_atomic_fetch_add(&flags[b], 1u, __ATOMIC_RELEASE, __HIP_MEMORY_SCOPE_AGENT);
    }

    // ---- consumer-side dot (independent of s2; hides the spin) ----
    float acc[RPW];
    #pragma unroll
    for (int r = 0; r < RPW; ++r)
        acc[r] = a0[r].x * w1a.x + a0[r].y * w1a.y + a0[r].z * w1a.z + a0[r].w * w1a.w
               + a1[r].x * w1b.x + a1[r].y * w1b.y + a1[r].z * w1b.z + a1[r].w * w1b.w;
    #pragma unroll
    for (int r = 0; r < RPW; ++r) {
        #pragma unroll
        for (int off = 1; off < 64; off <<= 1)
            acc[r] += __shfl_xor(acc[r], off, 64);
    }
    const float bval = bias[0];

    // ---- wait for this batch's s2 to be complete ----
    while (__hip_atomic_load(&flags[b], __ATOMIC_ACQUIRE, __HIP_MEMORY_SCOPE_AGENT) < (unsigned)WPB)
        __builtin_amdgcn_s_sleep(1);

    // ---- read s2[b,:] (L2-hot) and stream the output tile ----
    const f32x4* s2v = reinterpret_cast<const f32x4*>(s2 + (size_t)b * NN);
    f32x4 v2[NN / 4 / 64];            // 8 regs
    #pragma unroll
    for (int k = 0; k < NN / 4 / 64; ++k)
        v2[k] = s2v[lane + 64 * k];

    #pragma unroll
    for (int r = 0; r < RPW; ++r) {
        float v1 = acc[r] + bval;
        f32x4* orow = reinterpret_cast<f32x4*>(out + (size_t)(row0 + r) * NN);
        #pragma unroll
        for (int k = 0; k < NN / 4 / 64; ++k)
            orow[lane + 64 * k] = v2[k] + v1;
    }
}

extern "C" void kernel_launch(void* const* d_in, const int* in_sizes, int n_in,
                              void* d_out, int out_size, void* d_ws, size_t ws_size,
                              hipStream_t stream) {
    const float* m1   = (const float*)d_in[0];
    const float* m2   = (const float*)d_in[1];
    const float* w    = (const float*)d_in[2];
    const float* bias = (const float*)d_in[3];
    float* out = (float*)d_out;

    float* s2 = (float*)d_ws;                                   // 16384 floats (64 KB)
    unsigned int* flags = (unsigned int*)((char*)d_ws + ROWS * sizeof(float));  // 8 u32

    hipMemsetAsync(flags, 0, BB * sizeof(unsigned int), stream);

    // 4096 waves, 4 per block -> 1024 blocks (all co-resident)
    fused_all<<<NWAVES / 4, 256, 0, stream>>>(m1, m2, w, bias, s2, flags, out);
}

// Round 7
// 367.233 us; speedup vs baseline: 1.0317x; 1.0317x over previous
//
#include <hip/hip_runtime.h>

// out[b,n,m] = dot(m1[b,n,:], w[:512]) + dot(m2[b,m,:], w[512:]) + bias[0]
// B=8, N1=N2=2048, D=512, float32. Mandatory HBM: 67 MB read + 134 MB write.
//
// Single fused kernel, per-batch producer/consumer flags.
// R6 failed (378us) because the consumer spin used ACQUIRE loads: each one
// emits an L2-invalidate on gfx950's non-coherent per-XCD L2s -> continuous
// full-L2 invalidation storm. This version has ZERO cache invalidates:
//   - s2 stores:  relaxed agent-scope atomics (write through to coherence pt)
//   - flag inc:   RELEASE fetch_add (vmcnt(0) ordering, once per wave)
//   - spin:       RELAXED loads + s_sleep (no buffer_inv)
//   - s2 reads:   relaxed agent-scope atomic u64 loads (fresh from coherence
//                 point; stale local L2 impossible since nothing caches s2)
// Per-batch flags pipeline read & write phases: batch 0 stores while batch 7
// still reads. Deadlock-free: waves wait only on same-batch producers, and
// __launch_bounds__(256,4) => VGPR<=128 => all 1024 blocks co-resident.

#define DDIM 512
#define BB   8
#define NN   2048
#define ROWS (BB * NN)            // 16384 rows per matrix
#define RPW  4                    // rows per wave
#define NWAVES (ROWS / RPW)       // 4096
#define WPB  (NWAVES / BB)        // 512 waves per batch

typedef float f32x4 __attribute__((ext_vector_type(4)));

__global__ __launch_bounds__(256, 4)
void fused_all(const float* __restrict__ m1,
               const float* __restrict__ m2,
               const float* __restrict__ w,
               const float* __restrict__ bias,
               float* __restrict__ s2,
               unsigned int* __restrict__ flags,
               float* __restrict__ out) {
    int wave = (int)((blockIdx.x * blockDim.x + threadIdx.x) >> 6);  // 0..4095
    int lane = threadIdx.x & 63;
    int row0 = wave * RPW;            // [0,16384): both s2-row and out-row base
    int b    = wave >> 9;             // wave / 512 = batch

    const f32x4* wv1 = reinterpret_cast<const f32x4*>(w);
    const f32x4* wv2 = reinterpret_cast<const f32x4*>(w + DDIM);
    f32x4 w2a = wv2[lane], w2b = wv2[lane + 64];
    f32x4 w1a = wv1[lane], w1b = wv1[lane + 64];

    // ---- issue all row loads (m2 first: producer critical path) ----
    f32x4 c0[RPW], c1[RPW];           // m2 rows
    #pragma unroll
    for (int r = 0; r < RPW; ++r) {
        const f32x4* rp = reinterpret_cast<const f32x4*>(m2 + (size_t)(row0 + r) * DDIM);
        c0[r] = rp[lane];
        c1[r] = rp[lane + 64];
    }
    f32x4 a0[RPW], a1[RPW];           // m1 rows
    #pragma unroll
    for (int r = 0; r < RPW; ++r) {
        const f32x4* rp = reinterpret_cast<const f32x4*>(m1 + (size_t)(row0 + r) * DDIM);
        a0[r] = rp[lane];
        a1[r] = rp[lane + 64];
    }

    // ---- produce s2 slice ----
    float accs2[RPW];
    #pragma unroll
    for (int r = 0; r < RPW; ++r)
        accs2[r] = c0[r].x * w2a.x + c0[r].y * w2a.y + c0[r].z * w2a.z + c0[r].w * w2a.w
                 + c1[r].x * w2b.x + c1[r].y * w2b.y + c1[r].z * w2b.z + c1[r].w * w2b.w;
    #pragma unroll
    for (int r = 0; r < RPW; ++r) {
        #pragma unroll
        for (int off = 1; off < 64; off <<= 1)
            accs2[r] += __shfl_xor(accs2[r], off, 64);
    }
    if (lane == 0) {
        union { float f[2]; unsigned long long u; } p0, p1;
        p0.f[0] = accs2[0]; p0.f[1] = accs2[1];
        p1.f[0] = accs2[2]; p1.f[1] = accs2[3];
        unsigned long long* q = reinterpret_cast<unsigned long long*>(&s2[row0]);
        __hip_atomic_store(&q[0], p0.u, __ATOMIC_RELAXED, __HIP_MEMORY_SCOPE_AGENT);
        __hip_atomic_store(&q[1], p1.u, __ATOMIC_RELAXED, __HIP_MEMORY_SCOPE_AGENT);
        // release: vmcnt(0) orders the s2 stores at the coherence point first
        __hip_atomic_fetch_add(&flags[b], 1u, __ATOMIC_RELEASE, __HIP_MEMORY_SCOPE_AGENT);
    }

    // ---- consumer-side dot (independent of s2; hides the spin) ----
    float acc[RPW];
    #pragma unroll
    for (int r = 0; r < RPW; ++r)
        acc[r] = a0[r].x * w1a.x + a0[r].y * w1a.y + a0[r].z * w1a.z + a0[r].w * w1a.w
               + a1[r].x * w1b.x + a1[r].y * w1b.y + a1[r].z * w1b.z + a1[r].w * w1b.w;
    #pragma unroll
    for (int r = 0; r < RPW; ++r) {
        #pragma unroll
        for (int off = 1; off < 64; off <<= 1)
            acc[r] += __shfl_xor(acc[r], off, 64);
    }
    const float bval = bias[0];

    // ---- wait for this batch's s2 (RELAXED spin: no cache invalidates) ----
    while (__hip_atomic_load(&flags[b], __ATOMIC_RELAXED, __HIP_MEMORY_SCOPE_AGENT) < (unsigned)WPB)
        __builtin_amdgcn_s_sleep(8);

    // ---- read s2[b,:] via atomic u64 loads (coherence point, no inv) ----
    const unsigned long long* s2q =
        reinterpret_cast<const unsigned long long*>(s2 + (size_t)b * NN);
    f32x4 v2[8];
    #pragma unroll
    for (int k = 0; k < 8; ++k) {
        unsigned long long qa = __hip_atomic_load(&s2q[2 * (lane + 64 * k)],
                                                  __ATOMIC_RELAXED, __HIP_MEMORY_SCOPE_AGENT);
        unsigned long long qb = __hip_atomic_load(&s2q[2 * (lane + 64 * k) + 1],
                                                  __ATOMIC_RELAXED, __HIP_MEMORY_SCOPE_AGENT);
        union { unsigned long long u; float f[2]; } pa, pb;
        pa.u = qa; pb.u = qb;
        v2[k] = f32x4{pa.f[0], pa.f[1], pb.f[0], pb.f[1]};
    }

    // ---- stream the output tile: 4 rows x 2048 floats, plain f32x4 ----
    #pragma unroll
    for (int r = 0; r < RPW; ++r) {
        float v1 = acc[r] + bval;
        f32x4* orow = reinterpret_cast<f32x4*>(out + (size_t)(row0 + r) * NN);
        #pragma unroll
        for (int k = 0; k < 8; ++k)
            orow[lane + 64 * k] = v2[k] + v1;
    }
}

extern "C" void kernel_launch(void* const* d_in, const int* in_sizes, int n_in,
                              void* d_out, int out_size, void* d_ws, size_t ws_size,
                              hipStream_t stream) {
    const float* m1   = (const float*)d_in[0];
    const float* m2   = (const float*)d_in[1];
    const float* w    = (const float*)d_in[2];
    const float* bias = (const float*)d_in[3];
    float* out = (float*)d_out;

    float* s2 = (float*)d_ws;                                   // 16384 floats (64 KB)
    unsigned int* flags = (unsigned int*)((char*)d_ws + ROWS * sizeof(float));  // 8 u32

    hipMemsetAsync(flags, 0, BB * sizeof(unsigned int), stream);

    // 4096 waves, 4 per block -> 1024 blocks (all co-resident)
    fused_all<<<NWAVES / 4, 256, 0, stream>>>(m1, m2, w, bias, s2, flags, out);
}

// Round 8
// 162.878 us; speedup vs baseline: 2.3261x; 2.2546x over previous
//
#include <hip/hip_runtime.h>

// out[b,n,m] = dot(m1[b,n,:], w[:512]) + dot(m2[b,m,:], w[512:]) + bias[0]
// B=8, N1=N2=2048, D=512, float32. Mandatory HBM: ~67 MB read + 134 MB write.
//
// Single fused kernel, per-batch producer/consumer flags.
// R6 (378us) and R7 (367us) both died with ~identical times; the common
// element was the agent-scope RELEASE fetch_add per wave: on gfx950 a
// release RMW emits buffer_wbl2 (full L2 writeback scan). 4096 of those,
// serialized per-XCD TCC, = the ~400us. This version has ZERO cache
// maintenance instructions:
//   - s2 stores: RELAXED agent atomics  -> global_store with sc1 (L2-bypass,
//     coherence-point visible; proven correct in R7: absmax passed)
//   - ordering:  asm s_waitcnt vmcnt(0) + "memory" clobber (hand release)
//   - flag inc:  RELAXED fetch_add      -> no wbl2
//   - spin:      ONE thread per block polls (256x less contention), RELAXED
//     load + s_sleep backoff, then __syncthreads() broadcasts
//   - s2 reads:  plain f32x4 loads. Safe: s2 writes bypass L2, reads happen
//     only post-flag, so the first L2 fill pulls final data; replays are
//     deterministic so residual lines hold identical values.
// Deadlock-free: every block produces before spinning; batches retire in
// blockIdx order even at partial residency.

#define DDIM 512
#define BB   8
#define NN   2048
#define ROWS (BB * NN)            // 16384 rows per matrix
#define RPW  4                    // rows per wave
#define NWAVES (ROWS / RPW)       // 4096
#define WPB  (NWAVES / BB)        // 512 waves per batch

typedef float f32x4 __attribute__((ext_vector_type(4)));

__global__ __launch_bounds__(256, 4)
void fused_all(const float* __restrict__ m1,
               const float* __restrict__ m2,
               const float* __restrict__ w,
               const float* __restrict__ bias,
               float* __restrict__ s2,
               unsigned int* __restrict__ flags,
               float* __restrict__ out) {
    int wave = (int)((blockIdx.x * blockDim.x + threadIdx.x) >> 6);  // 0..4095
    int lane = threadIdx.x & 63;
    int row0 = wave * RPW;            // [0,16384): both s2-row and out-row base
    int b    = wave >> 9;             // wave / 512 = batch (uniform per block)

    const f32x4* wv1 = reinterpret_cast<const f32x4*>(w);
    const f32x4* wv2 = reinterpret_cast<const f32x4*>(w + DDIM);
    f32x4 w2a = wv2[lane], w2b = wv2[lane + 64];
    f32x4 w1a = wv1[lane], w1b = wv1[lane + 64];

    // ---- issue all row loads (m2 first: producer critical path) ----
    f32x4 c0[RPW], c1[RPW];           // m2 rows
    #pragma unroll
    for (int r = 0; r < RPW; ++r) {
        const f32x4* rp = reinterpret_cast<const f32x4*>(m2 + (size_t)(row0 + r) * DDIM);
        c0[r] = rp[lane];
        c1[r] = rp[lane + 64];
    }
    f32x4 a0[RPW], a1[RPW];           // m1 rows
    #pragma unroll
    for (int r = 0; r < RPW; ++r) {
        const f32x4* rp = reinterpret_cast<const f32x4*>(m1 + (size_t)(row0 + r) * DDIM);
        a0[r] = rp[lane];
        a1[r] = rp[lane + 64];
    }

    // ---- produce s2 slice ----
    float accs2[RPW];
    #pragma unroll
    for (int r = 0; r < RPW; ++r)
        accs2[r] = c0[r].x * w2a.x + c0[r].y * w2a.y + c0[r].z * w2a.z + c0[r].w * w2a.w
                 + c1[r].x * w2b.x + c1[r].y * w2b.y + c1[r].z * w2b.z + c1[r].w * w2b.w;
    #pragma unroll
    for (int r = 0; r < RPW; ++r) {
        #pragma unroll
        for (int off = 1; off < 64; off <<= 1)
            accs2[r] += __shfl_xor(accs2[r], off, 64);
    }
    if (lane == 0) {
        union { float f[2]; unsigned long long u; } p0, p1;
        p0.f[0] = accs2[0]; p0.f[1] = accs2[1];
        p1.f[0] = accs2[2]; p1.f[1] = accs2[3];
        unsigned long long* q = reinterpret_cast<unsigned long long*>(&s2[row0]);
        __hip_atomic_store(&q[0], p0.u, __ATOMIC_RELAXED, __HIP_MEMORY_SCOPE_AGENT);
        __hip_atomic_store(&q[1], p1.u, __ATOMIC_RELAXED, __HIP_MEMORY_SCOPE_AGENT);
        // hand-rolled release: drain the sc1 stores to the coherence point,
        // block compiler reordering; NO buffer_wbl2.
        asm volatile("s_waitcnt vmcnt(0)" ::: "memory");
        __hip_atomic_fetch_add(&flags[b], 1u, __ATOMIC_RELAXED, __HIP_MEMORY_SCOPE_AGENT);
    }

    // ---- consumer-side dot (independent of s2; hides producer latency) ----
    float acc[RPW];
    #pragma unroll
    for (int r = 0; r < RPW; ++r)
        acc[r] = a0[r].x * w1a.x + a0[r].y * w1a.y + a0[r].z * w1a.z + a0[r].w * w1a.w
               + a1[r].x * w1b.x + a1[r].y * w1b.y + a1[r].z * w1b.z + a1[r].w * w1b.w;
    #pragma unroll
    for (int r = 0; r < RPW; ++r) {
        #pragma unroll
        for (int off = 1; off < 64; off <<= 1)
            acc[r] += __shfl_xor(acc[r], off, 64);
    }
    const float bval = bias[0];

    // ---- wait for this batch's s2: ONE poller per block, then barrier ----
    if (threadIdx.x == 0) {
        while (__hip_atomic_load(&flags[b], __ATOMIC_RELAXED, __HIP_MEMORY_SCOPE_AGENT)
               < (unsigned)WPB)
            __builtin_amdgcn_s_sleep(16);
    }
    __syncthreads();

    // ---- read s2[b,:] with plain vector loads (L2-cacheable, fresh) ----
    const f32x4* s2v = reinterpret_cast<const f32x4*>(s2 + (size_t)b * NN);
    f32x4 v2[8];
    #pragma unroll
    for (int k = 0; k < 8; ++k)
        v2[k] = s2v[lane + 64 * k];

    // ---- stream the output tile: 4 rows x 2048 floats, plain f32x4 ----
    #pragma unroll
    for (int r = 0; r < RPW; ++r) {
        float v1 = acc[r] + bval;
        f32x4* orow = reinterpret_cast<f32x4*>(out + (size_t)(row0 + r) * NN);
        #pragma unroll
        for (int k = 0; k < 8; ++k)
            orow[lane + 64 * k] = v2[k] + v1;
    }
}

extern "C" void kernel_launch(void* const* d_in, const int* in_sizes, int n_in,
                              void* d_out, int out_size, void* d_ws, size_t ws_size,
                              hipStream_t stream) {
    const float* m1   = (const float*)d_in[0];
    const float* m2   = (const float*)d_in[1];
    const float* w    = (const float*)d_in[2];
    const float* bias = (const float*)d_in[3];
    float* out = (float*)d_out;

    float* s2 = (float*)d_ws;                                   // 16384 floats (64 KB)
    unsigned int* flags = (unsigned int*)((char*)d_ws + ROWS * sizeof(float));  // 8 u32

    hipMemsetAsync(flags, 0, BB * sizeof(unsigned int), stream);

    // 4096 waves, 4 per block -> 1024 blocks
    fused_all<<<NWAVES / 4, 256, 0, stream>>>(m1, m2, w, bias, s2, flags, out);
}

// Round 9
// 36.278 us; speedup vs baseline: 10.4437x; 4.4897x over previous
//
#include <hip/hip_runtime.h>

// out[b,n,m] = dot(m1[b,n,:], w[:512]) + dot(m2[b,m,:], w[512:]) + bias[0]
// B=8, N1=N2=2048, D=512, float32. Memory-bound: 67 MB read + 134 MB write.
//
// Final structure (proven 36.1 us in R5; persistent-kernel fusion attempts
// R6-R8 all regressed due to device-scope atomic RMW serialization ~40ns each):
// K1: s2[b,m] = dot(m2 row, w2). 4 rows/wave. 33.5 MB read-only pass.
// K2 (fused): each wave owns 4 FULL-WIDTH output rows (4 x 2048 floats).
//   - reads its 4 m1 rows (8 KB, exactly once grid-wide: no redundancy)
//   - preloads s2[b] (2048 floats) into 8 f32x4 regs, reused for all 4 rows
//   - 4 ILP butterfly reductions -> s1 values
//   - 32 KB plain streaming stores (f32x4, 1 KB contiguous per wave-step)
//   m1 reads overlap the write stream instead of being a serial phase.

#define DDIM 512
#define BB   8
#define NN   2048
#define ROWS (BB * NN)          // 16384 rows per matrix
#define RPW  4                  // rows per wave (both kernels)

typedef float f32x4 __attribute__((ext_vector_type(4)));

// K1: s2 only. Each wave: 4 consecutive m2 rows.
__global__ __launch_bounds__(256) void dot2_kernel(const float* __restrict__ m2,
                                                   const float* __restrict__ w,
                                                   float* __restrict__ s2) {
    int wave = (int)((blockIdx.x * blockDim.x + threadIdx.x) >> 6);
    int lane = threadIdx.x & 63;
    int row0 = wave * RPW;

    const f32x4* wv = reinterpret_cast<const f32x4*>(w + DDIM);
    f32x4 w0 = wv[lane];
    f32x4 w1 = wv[lane + 64];

    f32x4 a0[RPW], a1[RPW];
    #pragma unroll
    for (int r = 0; r < RPW; ++r) {
        const f32x4* rp = reinterpret_cast<const f32x4*>(m2 + (size_t)(row0 + r) * DDIM);
        a0[r] = rp[lane];
        a1[r] = rp[lane + 64];
    }

    float acc[RPW];
    #pragma unroll
    for (int r = 0; r < RPW; ++r)
        acc[r] = a0[r].x * w0.x + a0[r].y * w0.y + a0[r].z * w0.z + a0[r].w * w0.w
               + a1[r].x * w1.x + a1[r].y * w1.y + a1[r].z * w1.z + a1[r].w * w1.w;

    #pragma unroll
    for (int r = 0; r < RPW; ++r) {
        #pragma unroll
        for (int off = 1; off < 64; off <<= 1)
            acc[r] += __shfl_xor(acc[r], off, 64);
    }

    if (lane == 0) {
        #pragma unroll
        for (int r = 0; r < RPW; ++r)
            s2[row0 + r] = acc[r];
    }
}

// K2: fused. Each wave: 4 full-width output rows.
__global__ __launch_bounds__(256) void fused_kernel(const float* __restrict__ m1,
                                                    const float* __restrict__ w,
                                                    const float* __restrict__ s2,
                                                    const float* __restrict__ bias,
                                                    float* __restrict__ out) {
    int wave = (int)((blockIdx.x * blockDim.x + threadIdx.x) >> 6);  // 0..4095
    int lane = threadIdx.x & 63;
    int row0 = wave * RPW;               // global n-row in [0,16384)
    int b    = row0 >> 11;               // row0 / 2048

    const f32x4* wv = reinterpret_cast<const f32x4*>(w);
    f32x4 w0 = wv[lane];
    f32x4 w1 = wv[lane + 64];

    // m1 rows (issue all loads up front)
    f32x4 a0[RPW], a1[RPW];
    #pragma unroll
    for (int r = 0; r < RPW; ++r) {
        const f32x4* rp = reinterpret_cast<const f32x4*>(m1 + (size_t)(row0 + r) * DDIM);
        a0[r] = rp[lane];
        a1[r] = rp[lane + 64];
    }

    // s2[b,:] -> 8 f32x4 per lane (32 VGPR), reused for all 4 rows (L2-hot)
    const f32x4* s2v = reinterpret_cast<const f32x4*>(s2 + (size_t)b * NN);
    f32x4 v2[NN / 4 / 64];               // 8
    #pragma unroll
    for (int k = 0; k < NN / 4 / 64; ++k)
        v2[k] = s2v[lane + 64 * k];

    float acc[RPW];
    #pragma unroll
    for (int r = 0; r < RPW; ++r)
        acc[r] = a0[r].x * w0.x + a0[r].y * w0.y + a0[r].z * w0.z + a0[r].w * w0.w
               + a1[r].x * w1.x + a1[r].y * w1.y + a1[r].z * w1.z + a1[r].w * w1.w;

    #pragma unroll
    for (int r = 0; r < RPW; ++r) {
        #pragma unroll
        for (int off = 1; off < 64; off <<= 1)
            acc[r] += __shfl_xor(acc[r], off, 64);
    }

    const float bval = bias[0];
    #pragma unroll
    for (int r = 0; r < RPW; ++r) {
        float v1 = acc[r] + bval;
        f32x4* orow = reinterpret_cast<f32x4*>(out + (size_t)(row0 + r) * NN);
        #pragma unroll
        for (int k = 0; k < NN / 4 / 64; ++k)
            orow[lane + 64 * k] = v2[k] + v1;
    }
}

extern "C" void kernel_launch(void* const* d_in, const int* in_sizes, int n_in,
                              void* d_out, int out_size, void* d_ws, size_t ws_size,
                              hipStream_t stream) {
    const float* m1   = (const float*)d_in[0];
    const float* m2   = (const float*)d_in[1];
    const float* w    = (const float*)d_in[2];
    const float* bias = (const float*)d_in[3];
    float* out = (float*)d_out;
    float* s2  = (float*)d_ws;   // 16384 floats

    // K1: 16384 rows / 4 per wave = 4096 waves = 1024 blocks
    dot2_kernel<<<ROWS / (RPW * 4), 256, 0, stream>>>(m2, w, s2);

    // K2: 16384 rows / 4 per wave = 4096 waves = 1024 blocks
    fused_kernel<<<ROWS / (RPW * 4), 256, 0, stream>>>(m1, w, s2, bias, out);
}